// Round 9
// baseline (202.251 us; speedup 1.0000x reference)
//
#include <hip/hip_runtime.h>
#include <hip/hip_bf16.h>
#include <stdint.h>

#define N_NODES 100000
#define N_EDGES 1200000
#define IN_CH 64
#define HID 16
#define OUT_CH 64

#define BN 100       // nodes per bucket (1000*100 == 100000 exactly)
#define NB 1000      // buckets
#define BCAP 2048    // fixed slot capacity per bucket (mean 1200, max ~1330 observed regime)
#define CAP 2048     // staged slots per chunk; n <= BCAP == CAP -> single chunk

// fused kernel geometry (R5 known-good structure: role-split blocks, 2 ky : 3 sc)
#define F_TPB 512
#define KY_BLOCKS ((N_NODES * 2 + F_TPB - 1) / F_TPB)   // 391
#define SC_EPB 2048
#define SC_EPT (SC_EPB / F_TPB)                          // 4 edges per thread
#define SC_BLOCKS ((N_EDGES + SC_EPB - 1) / SC_EPB)      // 586
#define F_GROUPS 196                                     // 196*5 = 980 blocks

typedef __hip_bfloat16 bf16;

__device__ __forceinline__ float b2f(bf16 v) { return __bfloat162float(v); }
__device__ __forceinline__ float lo_f(uint32_t p) { return __uint_as_float(p << 16); }
__device__ __forceinline__ float hi_f(uint32_t p) { return __uint_as_float(p & 0xffff0000u); }
__device__ __forceinline__ uint16_t f2bb(float v) {
    bf16 h = __float2bfloat16(v);
    return *reinterpret_cast<uint16_t*>(&h);
}

__device__ __forceinline__ float loadf(const void* p, size_t i, int bf) {
    return bf ? b2f(((const bf16*)p)[i]) : ((const float*)p)[i];
}
__device__ __forceinline__ uint32_t bfbits(const void* p, size_t i, int bf) {
    if (bf) return ((const uint16_t*)p)[i];
    return f2bb(((const float*)p)[i]);
}
__device__ __forceinline__ int ld_dst(const int* p, int j, int i64) {
    if (i64) return ((const int2*)p)[(size_t)N_EDGES + j].x;
    return p[(size_t)N_EDGES + j];
}
__device__ __forceinline__ int ld_src(const int* p, int j, int i64) {
    if (i64) return ((const int2*)p)[j].x;
    return p[j];
}

// dtype detection, replicated per block (64 broadcast loads, L1/L2-hot).
__device__ __forceinline__ int detect_bf(const void* x) {
    const uint16_t* u = (const uint16_t*)x;
    int cnt = 0;
    for (int i = 0; i < 64; ++i) {
        int e = (u[i] >> 7) & 0xff;
        cnt += (e >= 100 && e <= 140);
    }
    return cnt >= 50;
}
__device__ __forceinline__ int detect_i64(const int* ei) {
    const uint32_t* w = (const uint32_t*)ei;
    int z = 0;
    for (int i = 1; i < 64; i += 2) z += (w[i] == 0u);
    return z >= 16;
}

// Fused k_y + bscatter (R5 structure, VERBATIM). Roles split by blockIdx, 2:3.
__global__ void __launch_bounds__(F_TPB) k_fused(const void* __restrict__ x,
                                                 const int* __restrict__ ei,
                                                 const void* __restrict__ ea,
                                                 const void* __restrict__ W1l,
                                                 const void* __restrict__ W1r,
                                                 const void* __restrict__ b1l,
                                                 const void* __restrict__ b1r,
                                                 const void* __restrict__ W1e,
                                                 const void* __restrict__ b1e,
                                                 bf16* __restrict__ y,
                                                 bf16* __restrict__ zh,
                                                 float* __restrict__ wc,
                                                 int* __restrict__ gcnt,
                                                 uint2* __restrict__ slots,
                                                 uint16_t* __restrict__ ea2v) {
    // union'd LDS: ky needs 8.3 KB, sc needs 35.7 KB
    __shared__ __align__(16) char smem[36608];
    __shared__ int wsum[8];
    __shared__ int s_flags;
    int t = threadIdx.x;
    int g = blockIdx.x / 5, r = blockIdx.x % 5;
    if (t == 0) s_flags = detect_bf(x) | (detect_i64(ei) << 1);

    if (r < 2) {
        // ---------------- ky role ----------------
        int kyid = g * 2 + r;
        if (kyid >= KY_BLOCKS) return;
        float* w = (float*)smem;            // [k][32]: cols 0-15 W1l, 16-31 W1r
        float* bz = (float*)(smem + 8192);  // [16]
        __syncthreads();
        int bf = s_flags & 1;
        for (int i = t; i < IN_CH * 32; i += F_TPB) {
            int k = i >> 5, cc = i & 31;
            w[i] = (cc < 16) ? loadf(W1l, k * HID + cc, bf)
                             : loadf(W1r, k * HID + (cc - 16), bf);
        }
        if (t < HID) bz[t] = loadf(b1l, t, bf) + loadf(b1r, t, bf);
        __syncthreads();
        if (kyid == 0 && t < HID) {
            int j = t;
            float s0 = 0.f, s1 = 0.f, s2 = 0.f, s3 = 0.f;
            for (int k = 0; k < IN_CH; ++k) {
                float wl = w[k * 32 + j];
                s0 += loadf(W1e, k, bf) * wl;
                s1 += loadf(W1e, IN_CH + k, bf) * wl;
                s2 += loadf(W1e, 2 * IN_CH + k, bf) * wl;
                s3 += loadf(b1e, k, bf) * wl;
            }
            wc[j] = s0;
            wc[HID + j] = s1;
            wc[2 * HID + j] = s2;
            wc[3 * HID + j] = s3;
        }
        int tid = kyid * F_TPB + t;
        int row = tid >> 1;
        if (row >= N_NODES) return;
        int half = tid & 1, cs = half * 16;
        float acc[16];
#pragma unroll
        for (int j = 0; j < 16; ++j) acc[j] = 0.f;
        if (bf) {
            const uint4* xr = (const uint4*)((const uint16_t*)x + (size_t)row * IN_CH);
            uint4 q[8];
#pragma unroll
            for (int i = 0; i < 8; ++i) q[i] = xr[i];
            const uint32_t* qq = (const uint32_t*)q;
#pragma unroll
            for (int k2 = 0; k2 < 32; ++k2) {
                uint32_t u = qq[k2];
                float x0 = lo_f(u), x1 = hi_f(u);
                const float* w0 = &w[(2 * k2) * 32 + cs];
                const float* w1 = w0 + 32;
#pragma unroll
                for (int j = 0; j < 16; ++j) acc[j] += x0 * w0[j] + x1 * w1[j];
            }
        } else {
            const float4* xr = (const float4*)((const float*)x + (size_t)row * IN_CH);
#pragma unroll
            for (int c = 0; c < 4; ++c) {
                float4 f[4];
#pragma unroll
                for (int i = 0; i < 4; ++i) f[i] = xr[c * 4 + i];
                const float* ff = (const float*)f;
#pragma unroll
                for (int kk = 0; kk < 16; ++kk) {
                    float xk = ff[kk];
                    const float* wr = &w[(c * 16 + kk) * 32 + cs];
#pragma unroll
                    for (int j = 0; j < 16; ++j) acc[j] += xk * wr[j];
                }
            }
        }
        if (half) {
#pragma unroll
            for (int j = 0; j < 16; ++j) acc[j] += bz[j];
        }
        uint32_t pk[8];
#pragma unroll
        for (int j2 = 0; j2 < 8; ++j2)
            pk[j2] = (uint32_t)f2bb(acc[2 * j2]) | ((uint32_t)f2bb(acc[2 * j2 + 1]) << 16);
        bf16* dst = half ? (zh + (size_t)row * HID) : (y + (size_t)row * HID);
        uint4* d4 = (uint4*)dst;
        d4[0] = make_uint4(pk[0], pk[1], pk[2], pk[3]);
        d4[1] = make_uint4(pk[4], pk[5], pk[6], pk[7]);
        return;
    }

    // ---------------- sc role ----------------
    int scid = g * 3 + (r - 2);
    if (scid >= SC_BLOCKS) return;
    uint2* lval = (uint2*)smem;                    // 16384 B
    int* lhist = (int*)(smem + 16384);             // 4000 B
    int* lscan = (int*)(smem + 20384);             // 4000 B
    int* ldelta = (int*)(smem + 24384);            // 4000 B
    uint16_t* lea = (uint16_t*)(smem + 28384);     // 4096 B
    uint16_t* lbid = (uint16_t*)(smem + 32480);    // 4096 B
    for (int i = t; i < NB; i += F_TPB) lhist[i] = 0;
    __syncthreads();
    int bf = s_flags & 1, i64 = (s_flags >> 1) & 1;
    int base = scid * SC_EPB;
    uint32_t rb[SC_EPT], srcv[SC_EPT], ea01v[SC_EPT], ea2r[SC_EPT];
#pragma unroll
    for (int i = 0; i < SC_EPT; ++i) {
        int e = base + i * F_TPB + t;
        rb[i] = 0xFFFFFFFFu;
        if (e < N_EDGES) {
            uint32_t d = (uint32_t)ld_dst(ei, e, i64);
            srcv[i] = (uint32_t)ld_src(ei, e, i64);
            ea01v[i] = bfbits(ea, (size_t)e * 3, bf) |
                       (bfbits(ea, (size_t)e * 3 + 1, bf) << 16);
            ea2r[i] = bfbits(ea, (size_t)e * 3 + 2, bf);
            uint32_t b = d / BN;
            uint32_t dl = d - b * BN;
            uint32_t rr = (uint32_t)atomicAdd(&lhist[b], 1);
            rb[i] = (b << 19) | (dl << 12) | rr;
        }
    }
    __syncthreads();
    int b0 = 2 * t, b1 = 2 * t + 1;
    int cnt0 = (b0 < NB) ? lhist[b0] : 0;
    int cnt1 = (b1 < NB) ? lhist[b1] : 0;
    int s_local = cnt0 + cnt1;
    int incl = s_local;
    int lane = t & 63;
#pragma unroll
    for (int d = 1; d < 64; d <<= 1) {
        int v = __shfl_up(incl, d);
        if (lane >= d) incl += v;
    }
    int w = t >> 6;
    if (lane == 63) wsum[w] = incl;
    __syncthreads();
    int wbase = 0, nst = 0;
#pragma unroll
    for (int i = 0; i < 8; ++i) {
        int v = wsum[i];
        wbase += (i < w) ? v : 0;
        nst += v;
    }
    int run = wbase + incl - s_local;
    if (b0 < NB) {
        lscan[b0] = run;
        if (cnt0) ldelta[b0] = b0 * BCAP + atomicAdd(&gcnt[b0], cnt0) - run;
    }
    run += cnt0;
    if (b1 < NB) {
        lscan[b1] = run;
        if (cnt1) ldelta[b1] = b1 * BCAP + atomicAdd(&gcnt[b1], cnt1) - run;
    }
    __syncthreads();
#pragma unroll
    for (int i = 0; i < SC_EPT; ++i) {
        if (rb[i] == 0xFFFFFFFFu) continue;
        uint32_t b = rb[i] >> 19;
        uint32_t dl = (rb[i] >> 12) & 0x7Fu;
        uint32_t rr = rb[i] & 0xFFFu;
        int lp = lscan[b] + (int)rr;
        lval[lp] = make_uint2(srcv[i] | (dl << 17), ea01v[i]);
        lea[lp] = (uint16_t)ea2r[i];
        lbid[lp] = (uint16_t)b;
    }
    __syncthreads();
    for (int p = t; p < nst; p += F_TPB) {
        int b = lbid[p];
        int gp = ldelta[b] + p;
        slots[gp] = lval[p];
        ea2v[gp] = lea[p];
    }
}

// Aggregation layer 1 v3: edge-split lanes. Counting sort by dl writes sorted
// VALUES (sst/sea01/sea2); lanes (2dl, 2dl+1) each take ALTERNATE edges of
// node dl, accumulate the FULL 16-col y row (2x16B loads/edge — same
// transaction count as col-split, half the serial chain and half the
// degree-tail), butterfly shfl_xor(1) combines. Shfl-based scan (2 barriers).
__global__ void __launch_bounds__(256) k_agg1(const uint2* __restrict__ slots,
                                              const uint16_t* __restrict__ ea2v,
                                              const int* __restrict__ gcnt,
                                              const bf16* __restrict__ y,
                                              const float* __restrict__ wc,
                                              bf16* __restrict__ zh,
                                              float* __restrict__ sa,
                                              uint32_t* __restrict__ ssrc,
                                              int* __restrict__ nof2) {
    __shared__ uint2 su[CAP];          // 16 KB staged {src|dl, ea01}
    __shared__ uint16_t ea2s[CAP];     // 4 KB staged ea2
    __shared__ uint32_t sst[CAP];      // 8 KB sorted src|dl
    __shared__ uint32_t sea01[CAP];    // 8 KB sorted ea01
    __shared__ uint16_t sea2[CAP];     // 4 KB sorted ea2
    __shared__ int hist[BN], noff[BN], cur[BN];
    __shared__ int wsum[4];
    __shared__ float swc[64];
    int t = threadIdx.x;
    if (t < 64) swc[t] = wc[t];
    int b = blockIdx.x;
    int n = gcnt[b];
    if (n > CAP) n = CAP;
    const uint2* sp = slots + (size_t)b * BCAP;
    const uint16_t* ep = ea2v + (size_t)b * BCAP;
    int dl = t >> 1, half = t & 1, cs = half * 8;

    for (int i = t; i < BN; i += 256) hist[i] = 0;
    for (int i = t; i < n; i += 256) {
        su[i] = sp[i];
        ea2s[i] = ep[i];
    }
    __syncthreads();
    // histogram (1 atomic/edge)
    for (int i = t; i < n; i += 256) atomicAdd(&hist[su[i].x >> 17], 1);
    __syncthreads();
    // shfl-based exclusive scan of hist (1 bin/thread, 2 barriers)
    {
        int own = (t < BN) ? hist[t] : 0;
        int incl = own;
        int lane = t & 63;
#pragma unroll
        for (int d = 1; d < 64; d <<= 1) {
            int v = __shfl_up(incl, d);
            if (lane >= d) incl += v;
        }
        int w = t >> 6;
        if (lane == 63) wsum[w] = incl;
        __syncthreads();
        int wbase = 0;
#pragma unroll
        for (int i = 0; i < 4; ++i) wbase += (i < w) ? wsum[i] : 0;
        if (t < BN) {
            int ex = wbase + incl - own;
            noff[t] = ex;
            cur[t] = ex;
        }
        __syncthreads();
    }
    // scatter: write sorted VALUES directly (1 atomic + 3 plain writes/edge)
    for (int i = t; i < n; i += 256) {
        uint2 u2 = su[i];
        int r = atomicAdd(&cur[u2.x >> 17], 1);
        sst[r] = u2.x;
        sea01[r] = u2.y;
        sea2[r] = ea2s[i];
    }
    __syncthreads();
    // persist for agg2 (coalesced LDS reads)
    for (int p = t; p < n; p += 256) ssrc[(size_t)b * BCAP + p] = sst[p];
    if (t < BN) nof2[b * 128 + t] = noff[t];
    // per-node gather, EDGE-SPLIT: lane takes k = kb+half, kb+half+2, ...
    float acc[16];
#pragma unroll
    for (int j = 0; j < 16; ++j) acc[j] = 0.f;
    float a0 = 0.f, a1 = 0.f, a2 = 0.f, degT = 0.f;
    if (dl < BN) {
        int kb = noff[dl];
        int ke = (dl == BN - 1) ? n : noff[dl + 1];
        degT = (float)(ke - kb);
        int k = kb + half;
        for (; k + 2 < ke; k += 4) {  // 2 edges in flight (4x16B loads)
            uint32_t s0 = sst[k], s1 = sst[k + 2];
            const uint32_t* r0 = (const uint32_t*)(y + (size_t)(s0 & 0x1FFFFu) * HID);
            const uint32_t* r1 = (const uint32_t*)(y + (size_t)(s1 & 0x1FFFFu) * HID);
            uint4 qa = *(const uint4*)r0;
            uint4 qb = *(const uint4*)(r0 + 4);
            uint4 qc = *(const uint4*)r1;
            uint4 qd = *(const uint4*)(r1 + 4);
            acc[0] += lo_f(qa.x) + lo_f(qc.x); acc[1] += hi_f(qa.x) + hi_f(qc.x);
            acc[2] += lo_f(qa.y) + lo_f(qc.y); acc[3] += hi_f(qa.y) + hi_f(qc.y);
            acc[4] += lo_f(qa.z) + lo_f(qc.z); acc[5] += hi_f(qa.z) + hi_f(qc.z);
            acc[6] += lo_f(qa.w) + lo_f(qc.w); acc[7] += hi_f(qa.w) + hi_f(qc.w);
            acc[8] += lo_f(qb.x) + lo_f(qd.x); acc[9] += hi_f(qb.x) + hi_f(qd.x);
            acc[10] += lo_f(qb.y) + lo_f(qd.y); acc[11] += hi_f(qb.y) + hi_f(qd.y);
            acc[12] += lo_f(qb.z) + lo_f(qd.z); acc[13] += hi_f(qb.z) + hi_f(qd.z);
            acc[14] += lo_f(qb.w) + lo_f(qd.w); acc[15] += hi_f(qb.w) + hi_f(qd.w);
            uint32_t e0 = sea01[k], e1 = sea01[k + 2];
            a0 += lo_f(e0) + lo_f(e1);
            a1 += hi_f(e0) + hi_f(e1);
            a2 += __uint_as_float((uint32_t)sea2[k] << 16) +
                  __uint_as_float((uint32_t)sea2[k + 2] << 16);
        }
        for (; k < ke; k += 2) {
            uint32_t s0 = sst[k];
            const uint32_t* r0 = (const uint32_t*)(y + (size_t)(s0 & 0x1FFFFu) * HID);
            uint4 qa = *(const uint4*)r0;
            uint4 qb = *(const uint4*)(r0 + 4);
            acc[0] += lo_f(qa.x); acc[1] += hi_f(qa.x);
            acc[2] += lo_f(qa.y); acc[3] += hi_f(qa.y);
            acc[4] += lo_f(qa.z); acc[5] += hi_f(qa.z);
            acc[6] += lo_f(qa.w); acc[7] += hi_f(qa.w);
            acc[8] += lo_f(qb.x); acc[9] += hi_f(qb.x);
            acc[10] += lo_f(qb.y); acc[11] += hi_f(qb.y);
            acc[12] += lo_f(qb.z); acc[13] += hi_f(qb.z);
            acc[14] += lo_f(qb.w); acc[15] += hi_f(qb.w);
            uint32_t e0 = sea01[k];
            a0 += lo_f(e0);
            a1 += hi_f(e0);
            a2 += __uint_as_float((uint32_t)sea2[k] << 16);
        }
    }
    // butterfly combine across the lane pair, then epilogue (registers only)
    if (dl < BN) {
#pragma unroll
        for (int j = 0; j < 16; ++j) acc[j] += __shfl_xor(acc[j], 1);
        a0 += __shfl_xor(a0, 1);
        a1 += __shfl_xor(a1, 1);
        a2 += __shfl_xor(a2, 1);
        size_t i = (size_t)b * BN + dl;
        float inv = 1.0f / fmaxf(degT, 1.0f);
        uint4 zq = *(const uint4*)(zh + i * HID + cs);
        float zf[8] = {lo_f(zq.x), hi_f(zq.x), lo_f(zq.y), hi_f(zq.y),
                       lo_f(zq.z), hi_f(zq.z), lo_f(zq.w), hi_f(zq.w)};
        uint32_t pk[4];
#pragma unroll
        for (int j = 0; j < 4; ++j) {
            float t0 = (acc[cs + 2 * j] + a0 * swc[cs + 2 * j] + a1 * swc[16 + cs + 2 * j] +
                        a2 * swc[32 + cs + 2 * j] + degT * swc[48 + cs + 2 * j]) * inv;
            float t1 = (acc[cs + 2 * j + 1] + a0 * swc[cs + 2 * j + 1] + a1 * swc[17 + cs + 2 * j] +
                        a2 * swc[33 + cs + 2 * j] + degT * swc[49 + cs + 2 * j]) * inv;
            float h0 = fmaxf(t0 + zf[2 * j], 0.f);
            float h1 = fmaxf(t1 + zf[2 * j + 1], 0.f);
            pk[j] = (uint32_t)f2bb(h0) | ((uint32_t)f2bb(h1) << 16);
        }
        *(uint4*)(zh + i * HID + cs) = make_uint4(pk[0], pk[1], pk[2], pk[3]);
        if (half == 0) {
            sa[i * 3 + 0] = a0;
            sa[i * 3 + 1] = a1;
            sa[i * 3 + 2] = a2;
        }
    }
}

// Aggregation layer 2 v3 + output epilogue: linear walk of agg1's persisted
// sorted stream with EDGE-SPLIT lanes (full 16-col row per edge, butterfly
// combine); fused 16->64 matmul.
__global__ void __launch_bounds__(256) k_agg2(const void* __restrict__ x,
                                              const uint32_t* __restrict__ ssrc,
                                              const int* __restrict__ nof2,
                                              const int* __restrict__ gcnt,
                                              const bf16* __restrict__ zh,  // holds h
                                              const float* __restrict__ sa,
                                              const void* __restrict__ W2l,
                                              const void* __restrict__ b2l,
                                              const void* __restrict__ W2r,
                                              const void* __restrict__ b2r,
                                              const void* __restrict__ W2e,
                                              const void* __restrict__ b2e,
                                              void* __restrict__ out) {
    __shared__ uint32_t ss[CAP];         // 8 KB sorted src|dl stream
    __shared__ int snoff[BN];
    __shared__ float facc[BN * HID];     // 6.4 KB
    __shared__ bf16 hl[BN * HID];        // 3.2 KB
    __shared__ float w2l[HID * OUT_CH];  // 4 KB
    __shared__ float w2r[HID * OUT_CH];  // 4 KB
    __shared__ float swe[3 * HID];
    __shared__ float sbe[HID];
    __shared__ float sbb[OUT_CH];
    __shared__ int s_bf;
    int t = threadIdx.x;
    if (t == 0) s_bf = detect_bf(x);
    __syncthreads();
    int bf = s_bf;
    for (int i = t; i < HID * OUT_CH; i += 256) {
        w2l[i] = loadf(W2l, i, bf);
        w2r[i] = loadf(W2r, i, bf);
    }
    if (t < 3 * HID) swe[t] = loadf(W2e, t, bf);
    if (t < HID) sbe[t] = loadf(b2e, t, bf);
    if (t < OUT_CH) sbb[t] = loadf(b2l, t, bf) + loadf(b2r, t, bf);
    int b = blockIdx.x;
    int n = gcnt[b];
    if (n > CAP) n = CAP;
    for (int i = t; i < n; i += 256) ss[i] = ssrc[(size_t)b * BCAP + i];
    if (t < BN) snoff[t] = nof2[b * 128 + t];
    __syncthreads();
    int dl = t >> 1, half = t & 1, cs = half * 8;
    float acc[16];
#pragma unroll
    for (int j = 0; j < 16; ++j) acc[j] = 0.f;
    float degT = 0.f;
    if (dl < BN) {
        int kb = snoff[dl];
        int ke = (dl == BN - 1) ? n : snoff[dl + 1];
        degT = (float)(ke - kb);
        int k = kb + half;
        for (; k + 2 < ke; k += 4) {
            uint32_t s0 = ss[k], s1 = ss[k + 2];
            const uint32_t* r0 = (const uint32_t*)(zh + (size_t)(s0 & 0x1FFFFu) * HID);
            const uint32_t* r1 = (const uint32_t*)(zh + (size_t)(s1 & 0x1FFFFu) * HID);
            uint4 qa = *(const uint4*)r0;
            uint4 qb = *(const uint4*)(r0 + 4);
            uint4 qc = *(const uint4*)r1;
            uint4 qd = *(const uint4*)(r1 + 4);
            acc[0] += lo_f(qa.x) + lo_f(qc.x); acc[1] += hi_f(qa.x) + hi_f(qc.x);
            acc[2] += lo_f(qa.y) + lo_f(qc.y); acc[3] += hi_f(qa.y) + hi_f(qc.y);
            acc[4] += lo_f(qa.z) + lo_f(qc.z); acc[5] += hi_f(qa.z) + hi_f(qc.z);
            acc[6] += lo_f(qa.w) + lo_f(qc.w); acc[7] += hi_f(qa.w) + hi_f(qc.w);
            acc[8] += lo_f(qb.x) + lo_f(qd.x); acc[9] += hi_f(qb.x) + hi_f(qd.x);
            acc[10] += lo_f(qb.y) + lo_f(qd.y); acc[11] += hi_f(qb.y) + hi_f(qd.y);
            acc[12] += lo_f(qb.z) + lo_f(qd.z); acc[13] += hi_f(qb.z) + hi_f(qd.z);
            acc[14] += lo_f(qb.w) + lo_f(qd.w); acc[15] += hi_f(qb.w) + hi_f(qd.w);
        }
        for (; k < ke; k += 2) {
            uint32_t s0 = ss[k];
            const uint32_t* r0 = (const uint32_t*)(zh + (size_t)(s0 & 0x1FFFFu) * HID);
            uint4 qa = *(const uint4*)r0;
            uint4 qb = *(const uint4*)(r0 + 4);
            acc[0] += lo_f(qa.x); acc[1] += hi_f(qa.x);
            acc[2] += lo_f(qa.y); acc[3] += hi_f(qa.y);
            acc[4] += lo_f(qa.z); acc[5] += hi_f(qa.z);
            acc[6] += lo_f(qa.w); acc[7] += hi_f(qa.w);
            acc[8] += lo_f(qb.x); acc[9] += hi_f(qb.x);
            acc[10] += lo_f(qb.y); acc[11] += hi_f(qb.y);
            acc[12] += lo_f(qb.z); acc[13] += hi_f(qb.z);
            acc[14] += lo_f(qb.w); acc[15] += hi_f(qb.w);
        }
    }
    // butterfly combine, then per-node mean path -> facc; self h -> hl
    if (dl < BN) {
#pragma unroll
        for (int j = 0; j < 16; ++j) acc[j] += __shfl_xor(acc[j], 1);
        size_t i = (size_t)b * BN + dl;
        float inv = 1.0f / fmaxf(degT, 1.0f);
        float a0 = sa[i * 3 + 0], a1 = sa[i * 3 + 1], a2 = sa[i * 3 + 2];
        float4 f0, f1;
        float* fo = (float*)&f0;
        float* f1o = (float*)&f1;
#pragma unroll
        for (int j = 0; j < 4; ++j) {
            fo[j] = (acc[cs + j] + a0 * swe[cs + j] + a1 * swe[16 + cs + j] +
                     a2 * swe[32 + cs + j] + degT * sbe[cs + j]) * inv;
            f1o[j] = (acc[cs + 4 + j] + a0 * swe[cs + 4 + j] + a1 * swe[16 + cs + 4 + j] +
                      a2 * swe[32 + cs + 4 + j] + degT * sbe[cs + 4 + j]) * inv;
        }
        *(float4*)&facc[dl * HID + cs] = f0;
        *(float4*)&facc[dl * HID + cs + 4] = f1;
        *(uint4*)&hl[dl * HID + cs] = *(const uint4*)(zh + i * HID + cs);
    }
    __syncthreads();
    for (int idx = t; idx < BN * OUT_CH; idx += 256) {
        int dli = idx >> 6, j = idx & 63;
        size_t i = (size_t)b * BN + dli;
        float o = sbb[j];
#pragma unroll
        for (int cc = 0; cc < HID; ++cc)
            o += facc[dli * HID + cc] * w2l[cc * OUT_CH + j] +
                 b2f(hl[dli * HID + cc]) * w2r[cc * OUT_CH + j];
        if (bf)
            ((bf16*)out)[i * OUT_CH + j] = __float2bfloat16(o);
        else
            ((float*)out)[i * OUT_CH + j] = o;
    }
}

extern "C" void kernel_launch(void* const* d_in, const int* in_sizes, int n_in,
                              void* d_out, int out_size, void* d_ws, size_t ws_size,
                              hipStream_t stream) {
    const void* x   = d_in[0];
    const int*  ei  = (const int*)d_in[1];
    const void* ea  = d_in[2];
    const void* W1l = d_in[3];
    const void* b1l = d_in[4];
    const void* W1r = d_in[5];
    const void* b1r = d_in[6];
    const void* W1e = d_in[7];
    const void* b1e = d_in[8];
    const void* W2l = d_in[9];
    const void* b2l = d_in[10];
    const void* W2r = d_in[11];
    const void* b2r = d_in[12];
    const void* W2e = d_in[13];
    const void* b2e = d_in[14];

    const size_t N16 = (size_t)N_NODES * HID;
    char* p = (char*)d_ws;
    uint2*    slots = (uint2*)p;    p += (size_t)NB * BCAP * sizeof(uint2);     // 16.4 MB
    uint16_t* ea2v  = (uint16_t*)p; p += (size_t)NB * BCAP * sizeof(uint16_t);  // 4.1 MB
    uint32_t* ssrc  = (uint32_t*)p; p += (size_t)NB * BCAP * sizeof(uint32_t);  // 8.2 MB
    int*      nof2  = (int*)p;      p += (size_t)NB * 128 * sizeof(int);        // 0.5 MB
    bf16*     y     = (bf16*)p;     p += N16 * sizeof(bf16);                    // 3.2 MB
    bf16*     zh    = (bf16*)p;     p += N16 * sizeof(bf16);                    // 3.2 MB
    float*    sa    = (float*)p;    p += (size_t)3 * N_NODES * sizeof(float);   // 1.2 MB
    int*      gcnt  = (int*)p;      p += NB * sizeof(int);
    float*    wc    = (float*)p;    p += 64 * sizeof(float);
    // total ~37 MB

    hipMemsetAsync(gcnt, 0, NB * sizeof(int), stream);
    k_fused<<<F_GROUPS * 5, F_TPB, 0, stream>>>(x, ei, ea, W1l, W1r, b1l, b1r, W1e, b1e,
                                                y, zh, wc, gcnt, slots, ea2v);
    k_agg1<<<NB, 256, 0, stream>>>(slots, ea2v, gcnt, y, wc, zh, sa, ssrc, nof2);
    k_agg2<<<NB, 256, 0, stream>>>(x, ssrc, nof2, gcnt, zh, sa, W2l, b2l, W2r, b2r,
                                   W2e, b2e, d_out);
}

// Round 11
// 198.119 us; speedup vs baseline: 1.0209x; 1.0209x over previous
//
#include <hip/hip_runtime.h>
#include <hip/hip_bf16.h>
#include <stdint.h>

#define N_NODES 100000
#define N_EDGES 1200000
#define IN_CH 64
#define HID 16
#define OUT_CH 64

#define BN 100       // nodes per bucket (1000*100 == 100000 exactly)
#define NB 1000      // buckets
#define BCAP 2048    // fixed slot capacity per bucket (mean 1200, max ~1330 observed regime)
#define CAP 2048     // staged slots per chunk; n <= BCAP == CAP -> single chunk

// fused kernel geometry v2: ONE scheduling round (490 blocks <= 512 = 2/CU).
//   ky: 196 blocks x 512 rows (2 rows/thread), sc: 293 blocks x 4096 edges
//   (two-pass staging through 2048-entry LDS; reservation atomics halved).
#define F_TPB 512
#define KY_BLOCKS 196
#define KY_RPB 512
#define SC_EPB 4096
#define SC_EPT (SC_EPB / F_TPB)                          // 8 edges per thread
#define SC_BLOCKS ((N_EDGES + SC_EPB - 1) / SC_EPB)      // 293
#define F_GROUPS 98                                      // 98*5 = 490 blocks (2 ky : 3 sc)

typedef __hip_bfloat16 bf16;

__device__ __forceinline__ float b2f(bf16 v) { return __bfloat162float(v); }
__device__ __forceinline__ float lo_f(uint32_t p) { return __uint_as_float(p << 16); }
__device__ __forceinline__ float hi_f(uint32_t p) { return __uint_as_float(p & 0xffff0000u); }
__device__ __forceinline__ uint16_t f2bb(float v) {
    bf16 h = __float2bfloat16(v);
    return *reinterpret_cast<uint16_t*>(&h);
}

__device__ __forceinline__ float loadf(const void* p, size_t i, int bf) {
    return bf ? b2f(((const bf16*)p)[i]) : ((const float*)p)[i];
}
__device__ __forceinline__ uint32_t bfbits(const void* p, size_t i, int bf) {
    if (bf) return ((const uint16_t*)p)[i];
    return f2bb(((const float*)p)[i]);
}
__device__ __forceinline__ int ld_dst(const int* p, int j, int i64) {
    if (i64) return ((const int2*)p)[(size_t)N_EDGES + j].x;
    return p[(size_t)N_EDGES + j];
}
__device__ __forceinline__ int ld_src(const int* p, int j, int i64) {
    if (i64) return ((const int2*)p)[j].x;
    return p[j];
}

// dtype detection, replicated per block (64 broadcast loads, L1/L2-hot).
__device__ __forceinline__ int detect_bf(const void* x) {
    const uint16_t* u = (const uint16_t*)x;
    int cnt = 0;
    for (int i = 0; i < 64; ++i) {
        int e = (u[i] >> 7) & 0xff;
        cnt += (e >= 100 && e <= 140);
    }
    return cnt >= 50;
}
__device__ __forceinline__ int detect_i64(const int* ei) {
    const uint32_t* w = (const uint32_t*)ei;
    int z = 0;
    for (int i = 1; i < 64; i += 2) z += (w[i] == 0u);
    return z >= 16;
}

// Fused k_y + bscatter v2. Roles split by blockIdx, interleaved 2:3; single
// scheduling round (490 blocks at 2 blocks/CU). launch_bounds caps VGPR<=128.
__global__ void __launch_bounds__(F_TPB, 4) k_fused(const void* __restrict__ x,
                                                    const int* __restrict__ ei,
                                                    const void* __restrict__ ea,
                                                    const void* __restrict__ W1l,
                                                    const void* __restrict__ W1r,
                                                    const void* __restrict__ b1l,
                                                    const void* __restrict__ b1r,
                                                    const void* __restrict__ W1e,
                                                    const void* __restrict__ b1e,
                                                    bf16* __restrict__ y,
                                                    bf16* __restrict__ zh,
                                                    float* __restrict__ wc,
                                                    int* __restrict__ gcnt,
                                                    uint2* __restrict__ slots,
                                                    uint16_t* __restrict__ ea2v) {
    // union'd LDS: ky needs 8.3 KB, sc needs 35.7 KB
    __shared__ __align__(16) char smem[36608];
    __shared__ int wsum[8];
    __shared__ int s_flags;
    int t = threadIdx.x;
    int g = blockIdx.x / 5, r = blockIdx.x % 5;
    if (t == 0) s_flags = detect_bf(x) | (detect_i64(ei) << 1);

    if (r < 2) {
        // ---------------- ky role: 512 rows/block, 2 rows/thread ----------------
        int kyid = g * 2 + r;  // [0, 196)
        float* w = (float*)smem;            // [k][32]: cols 0-15 W1l, 16-31 W1r
        float* bz = (float*)(smem + 8192);  // [16]
        __syncthreads();
        int bf = s_flags & 1;
        for (int i = t; i < IN_CH * 32; i += F_TPB) {
            int k = i >> 5, cc = i & 31;
            w[i] = (cc < 16) ? loadf(W1l, k * HID + cc, bf)
                             : loadf(W1r, k * HID + (cc - 16), bf);
        }
        if (t < HID) bz[t] = loadf(b1l, t, bf) + loadf(b1r, t, bf);
        __syncthreads();
        if (kyid == 0 && t < HID) {
            int j = t;
            float s0 = 0.f, s1 = 0.f, s2 = 0.f, s3 = 0.f;
            for (int k = 0; k < IN_CH; ++k) {
                float wl = w[k * 32 + j];
                s0 += loadf(W1e, k, bf) * wl;
                s1 += loadf(W1e, IN_CH + k, bf) * wl;
                s2 += loadf(W1e, 2 * IN_CH + k, bf) * wl;
                s3 += loadf(b1e, k, bf) * wl;
            }
            wc[j] = s0;
            wc[HID + j] = s1;
            wc[2 * HID + j] = s2;
            wc[3 * HID + j] = s3;
        }
        int half = t & 1, cs = half * 16;
        for (int rep = 0; rep < 2; ++rep) {
            int row = kyid * KY_RPB + rep * 256 + (t >> 1);
            if (row >= N_NODES) continue;
            float acc[16];
#pragma unroll
            for (int j = 0; j < 16; ++j) acc[j] = 0.f;
            if (bf) {
                const uint4* xr = (const uint4*)((const uint16_t*)x + (size_t)row * IN_CH);
                uint4 q[8];
#pragma unroll
                for (int i = 0; i < 8; ++i) q[i] = xr[i];
                const uint32_t* qq = (const uint32_t*)q;
#pragma unroll
                for (int k2 = 0; k2 < 32; ++k2) {
                    uint32_t u = qq[k2];
                    float x0 = lo_f(u), x1 = hi_f(u);
                    const float* w0 = &w[(2 * k2) * 32 + cs];
                    const float* w1 = w0 + 32;
#pragma unroll
                    for (int j = 0; j < 16; ++j) acc[j] += x0 * w0[j] + x1 * w1[j];
                }
            } else {
                const float4* xr = (const float4*)((const float*)x + (size_t)row * IN_CH);
#pragma unroll
                for (int c = 0; c < 4; ++c) {
                    float4 f[4];
#pragma unroll
                    for (int i = 0; i < 4; ++i) f[i] = xr[c * 4 + i];
                    const float* ff = (const float*)f;
#pragma unroll
                    for (int kk = 0; kk < 16; ++kk) {
                        float xk = ff[kk];
                        const float* wr = &w[(c * 16 + kk) * 32 + cs];
#pragma unroll
                        for (int j = 0; j < 16; ++j) acc[j] += xk * wr[j];
                    }
                }
            }
            if (half) {
#pragma unroll
                for (int j = 0; j < 16; ++j) acc[j] += bz[j];
            }
            uint32_t pk[8];
#pragma unroll
            for (int j2 = 0; j2 < 8; ++j2)
                pk[j2] = (uint32_t)f2bb(acc[2 * j2]) | ((uint32_t)f2bb(acc[2 * j2 + 1]) << 16);
            bf16* dst = half ? (zh + (size_t)row * HID) : (y + (size_t)row * HID);
            uint4* d4 = (uint4*)dst;
            d4[0] = make_uint4(pk[0], pk[1], pk[2], pk[3]);
            d4[1] = make_uint4(pk[4], pk[5], pk[6], pk[7]);
        }
        return;
    }

    // ---------------- sc role: 4096 edges, two-pass staging ----------------
    int scid = g * 3 + (r - 2);
    if (scid >= SC_BLOCKS) return;
    uint2* lval = (uint2*)smem;                    // 16384 B (2048 slots)
    int* lhist = (int*)(smem + 16384);             // 4000 B
    int* lscan = (int*)(smem + 20384);             // 4000 B
    int* ldelta = (int*)(smem + 24384);            // 4000 B
    uint16_t* lea = (uint16_t*)(smem + 28384);     // 4096 B
    uint16_t* lbid = (uint16_t*)(smem + 32480);    // 4096 B
    for (int i = t; i < NB; i += F_TPB) lhist[i] = 0;
    __syncthreads();
    int bf = s_flags & 1, i64 = (s_flags >> 1) & 1;
    int base = scid * SC_EPB;
    // Pass 1: load everything coalesced; rank within bucket via LDS atomic.
    // rb pack: b[28:19] dl[18:12] r[11:0]  (r < 4096 fits 12 bits)
    uint32_t rb[SC_EPT], srcv[SC_EPT], ea01v[SC_EPT], ea2r[SC_EPT];
#pragma unroll
    for (int i = 0; i < SC_EPT; ++i) {
        int e = base + i * F_TPB + t;
        rb[i] = 0xFFFFFFFFu;
        if (e < N_EDGES) {
            uint32_t d = (uint32_t)ld_dst(ei, e, i64);
            srcv[i] = (uint32_t)ld_src(ei, e, i64);
            ea01v[i] = bfbits(ea, (size_t)e * 3, bf) |
                       (bfbits(ea, (size_t)e * 3 + 1, bf) << 16);
            ea2r[i] = bfbits(ea, (size_t)e * 3 + 2, bf);
            uint32_t b = d / BN;
            uint32_t dl = d - b * BN;
            uint32_t rr = (uint32_t)atomicAdd(&lhist[b], 1);
            rb[i] = (b << 19) | (dl << 12) | rr;
        }
    }
    __syncthreads();
    // Pass 2: scan lhist (2 bins/thread, shfl wave-scan + LDS hop); reserve
    // per-bucket space in fixed region b*BCAP via ONE global atomic/bucket.
    int b0 = 2 * t, b1 = 2 * t + 1;
    int cnt0 = (b0 < NB) ? lhist[b0] : 0;
    int cnt1 = (b1 < NB) ? lhist[b1] : 0;
    int s_local = cnt0 + cnt1;
    int incl = s_local;
    int lane = t & 63;
#pragma unroll
    for (int d = 1; d < 64; d <<= 1) {
        int v = __shfl_up(incl, d);
        if (lane >= d) incl += v;
    }
    int w = t >> 6;
    if (lane == 63) wsum[w] = incl;
    __syncthreads();
    int wbase = 0, nst = 0;
#pragma unroll
    for (int i = 0; i < 8; ++i) {
        int v = wsum[i];
        wbase += (i < w) ? v : 0;
        nst += v;
    }
    int run = wbase + incl - s_local;
    if (b0 < NB) {
        lscan[b0] = run;
        if (cnt0) ldelta[b0] = b0 * BCAP + atomicAdd(&gcnt[b0], cnt0) - run;
    }
    run += cnt0;
    if (b1 < NB) {
        lscan[b1] = run;
        if (cnt1) ldelta[b1] = b1 * BCAP + atomicAdd(&gcnt[b1], cnt1) - run;
    }
    __syncthreads();
    // Pass 3a: stage sorted positions [0,2048) and write them.
#pragma unroll
    for (int i = 0; i < SC_EPT; ++i) {
        if (rb[i] == 0xFFFFFFFFu) continue;
        uint32_t b = rb[i] >> 19;
        uint32_t dl = (rb[i] >> 12) & 0x7Fu;
        uint32_t rr = rb[i] & 0xFFFu;
        int lp = lscan[b] + (int)rr;
        if (lp < 2048) {
            lval[lp] = make_uint2(srcv[i] | (dl << 17), ea01v[i]);
            lea[lp] = (uint16_t)ea2r[i];
            lbid[lp] = (uint16_t)b;
        }
    }
    __syncthreads();
    int lim = nst < 2048 ? nst : 2048;
    for (int p = t; p < lim; p += F_TPB) {
        int b = lbid[p];
        int gp = ldelta[b] + p;
        slots[gp] = lval[p];
        ea2v[gp] = lea[p];
    }
    // Pass 3b: stage sorted positions [2048,4096) and write them.
    if (nst > 2048) {
        __syncthreads();
#pragma unroll
        for (int i = 0; i < SC_EPT; ++i) {
            if (rb[i] == 0xFFFFFFFFu) continue;
            uint32_t b = rb[i] >> 19;
            uint32_t dl = (rb[i] >> 12) & 0x7Fu;
            uint32_t rr = rb[i] & 0xFFFu;
            int lp = lscan[b] + (int)rr - 2048;
            if (lp >= 0) {
                lval[lp] = make_uint2(srcv[i] | (dl << 17), ea01v[i]);
                lea[lp] = (uint16_t)ea2r[i];
                lbid[lp] = (uint16_t)b;
            }
        }
        __syncthreads();
        int n2 = nst - 2048;
        for (int p2 = t; p2 < n2; p2 += F_TPB) {
            int b = lbid[p2];
            int gp = ldelta[b] + p2 + 2048;
            slots[gp] = lval[p2];
            ea2v[gp] = lea[p2];
        }
    }
}

// Aggregation layer 1 v3 (unchanged from R9): edge-split lanes, counting sort
// writes sorted VALUES, shfl scan, butterfly combine. Persists sst/noff.
__global__ void __launch_bounds__(256) k_agg1(const uint2* __restrict__ slots,
                                              const uint16_t* __restrict__ ea2v,
                                              const int* __restrict__ gcnt,
                                              const bf16* __restrict__ y,
                                              const float* __restrict__ wc,
                                              bf16* __restrict__ zh,
                                              float* __restrict__ sa,
                                              uint32_t* __restrict__ ssrc,
                                              int* __restrict__ nof2) {
    __shared__ uint2 su[CAP];          // 16 KB staged {src|dl, ea01}
    __shared__ uint16_t ea2s[CAP];     // 4 KB staged ea2
    __shared__ uint32_t sst[CAP];      // 8 KB sorted src|dl
    __shared__ uint32_t sea01[CAP];    // 8 KB sorted ea01
    __shared__ uint16_t sea2[CAP];     // 4 KB sorted ea2
    __shared__ int hist[BN], noff[BN], cur[BN];
    __shared__ int wsum[4];
    __shared__ float swc[64];
    int t = threadIdx.x;
    if (t < 64) swc[t] = wc[t];
    int b = blockIdx.x;
    int n = gcnt[b];
    if (n > CAP) n = CAP;
    const uint2* sp = slots + (size_t)b * BCAP;
    const uint16_t* ep = ea2v + (size_t)b * BCAP;
    int dl = t >> 1, half = t & 1, cs = half * 8;

    for (int i = t; i < BN; i += 256) hist[i] = 0;
    for (int i = t; i < n; i += 256) {
        su[i] = sp[i];
        ea2s[i] = ep[i];
    }
    __syncthreads();
    for (int i = t; i < n; i += 256) atomicAdd(&hist[su[i].x >> 17], 1);
    __syncthreads();
    {
        int own = (t < BN) ? hist[t] : 0;
        int incl = own;
        int lane = t & 63;
#pragma unroll
        for (int d = 1; d < 64; d <<= 1) {
            int v = __shfl_up(incl, d);
            if (lane >= d) incl += v;
        }
        int w = t >> 6;
        if (lane == 63) wsum[w] = incl;
        __syncthreads();
        int wbase = 0;
#pragma unroll
        for (int i = 0; i < 4; ++i) wbase += (i < w) ? wsum[i] : 0;
        if (t < BN) {
            int ex = wbase + incl - own;
            noff[t] = ex;
            cur[t] = ex;
        }
        __syncthreads();
    }
    for (int i = t; i < n; i += 256) {
        uint2 u2 = su[i];
        int r = atomicAdd(&cur[u2.x >> 17], 1);
        sst[r] = u2.x;
        sea01[r] = u2.y;
        sea2[r] = ea2s[i];
    }
    __syncthreads();
    for (int p = t; p < n; p += 256) ssrc[(size_t)b * BCAP + p] = sst[p];
    if (t < BN) nof2[b * 128 + t] = noff[t];
    float acc[16];
#pragma unroll
    for (int j = 0; j < 16; ++j) acc[j] = 0.f;
    float a0 = 0.f, a1 = 0.f, a2 = 0.f, degT = 0.f;
    if (dl < BN) {
        int kb = noff[dl];
        int ke = (dl == BN - 1) ? n : noff[dl + 1];
        degT = (float)(ke - kb);
        int k = kb + half;
        for (; k + 2 < ke; k += 4) {
            uint32_t s0 = sst[k], s1 = sst[k + 2];
            const uint32_t* r0 = (const uint32_t*)(y + (size_t)(s0 & 0x1FFFFu) * HID);
            const uint32_t* r1 = (const uint32_t*)(y + (size_t)(s1 & 0x1FFFFu) * HID);
            uint4 qa = *(const uint4*)r0;
            uint4 qb = *(const uint4*)(r0 + 4);
            uint4 qc = *(const uint4*)r1;
            uint4 qd = *(const uint4*)(r1 + 4);
            acc[0] += lo_f(qa.x) + lo_f(qc.x); acc[1] += hi_f(qa.x) + hi_f(qc.x);
            acc[2] += lo_f(qa.y) + lo_f(qc.y); acc[3] += hi_f(qa.y) + hi_f(qc.y);
            acc[4] += lo_f(qa.z) + lo_f(qc.z); acc[5] += hi_f(qa.z) + hi_f(qc.z);
            acc[6] += lo_f(qa.w) + lo_f(qc.w); acc[7] += hi_f(qa.w) + hi_f(qc.w);
            acc[8] += lo_f(qb.x) + lo_f(qd.x); acc[9] += hi_f(qb.x) + hi_f(qd.x);
            acc[10] += lo_f(qb.y) + lo_f(qd.y); acc[11] += hi_f(qb.y) + hi_f(qd.y);
            acc[12] += lo_f(qb.z) + lo_f(qd.z); acc[13] += hi_f(qb.z) + hi_f(qd.z);
            acc[14] += lo_f(qb.w) + lo_f(qd.w); acc[15] += hi_f(qb.w) + hi_f(qd.w);
            uint32_t e0 = sea01[k], e1 = sea01[k + 2];
            a0 += lo_f(e0) + lo_f(e1);
            a1 += hi_f(e0) + hi_f(e1);
            a2 += __uint_as_float((uint32_t)sea2[k] << 16) +
                  __uint_as_float((uint32_t)sea2[k + 2] << 16);
        }
        for (; k < ke; k += 2) {
            uint32_t s0 = sst[k];
            const uint32_t* r0 = (const uint32_t*)(y + (size_t)(s0 & 0x1FFFFu) * HID);
            uint4 qa = *(const uint4*)r0;
            uint4 qb = *(const uint4*)(r0 + 4);
            acc[0] += lo_f(qa.x); acc[1] += hi_f(qa.x);
            acc[2] += lo_f(qa.y); acc[3] += hi_f(qa.y);
            acc[4] += lo_f(qa.z); acc[5] += hi_f(qa.z);
            acc[6] += lo_f(qa.w); acc[7] += hi_f(qa.w);
            acc[8] += lo_f(qb.x); acc[9] += hi_f(qb.x);
            acc[10] += lo_f(qb.y); acc[11] += hi_f(qb.y);
            acc[12] += lo_f(qb.z); acc[13] += hi_f(qb.z);
            acc[14] += lo_f(qb.w); acc[15] += hi_f(qb.w);
            uint32_t e0 = sea01[k];
            a0 += lo_f(e0);
            a1 += hi_f(e0);
            a2 += __uint_as_float((uint32_t)sea2[k] << 16);
        }
    }
    if (dl < BN) {
#pragma unroll
        for (int j = 0; j < 16; ++j) acc[j] += __shfl_xor(acc[j], 1);
        a0 += __shfl_xor(a0, 1);
        a1 += __shfl_xor(a1, 1);
        a2 += __shfl_xor(a2, 1);
        size_t i = (size_t)b * BN + dl;
        float inv = 1.0f / fmaxf(degT, 1.0f);
        uint4 zq = *(const uint4*)(zh + i * HID + cs);
        float zf[8] = {lo_f(zq.x), hi_f(zq.x), lo_f(zq.y), hi_f(zq.y),
                       lo_f(zq.z), hi_f(zq.z), lo_f(zq.w), hi_f(zq.w)};
        uint32_t pk[4];
#pragma unroll
        for (int j = 0; j < 4; ++j) {
            float t0 = (acc[cs + 2 * j] + a0 * swc[cs + 2 * j] + a1 * swc[16 + cs + 2 * j] +
                        a2 * swc[32 + cs + 2 * j] + degT * swc[48 + cs + 2 * j]) * inv;
            float t1 = (acc[cs + 2 * j + 1] + a0 * swc[cs + 2 * j + 1] + a1 * swc[17 + cs + 2 * j] +
                        a2 * swc[33 + cs + 2 * j] + degT * swc[49 + cs + 2 * j]) * inv;
            float h0 = fmaxf(t0 + zf[2 * j], 0.f);
            float h1 = fmaxf(t1 + zf[2 * j + 1], 0.f);
            pk[j] = (uint32_t)f2bb(h0) | ((uint32_t)f2bb(h1) << 16);
        }
        *(uint4*)(zh + i * HID + cs) = make_uint4(pk[0], pk[1], pk[2], pk[3]);
        if (half == 0) {
            sa[i * 3 + 0] = a0;
            sa[i * 3 + 1] = a1;
            sa[i * 3 + 2] = a2;
        }
    }
}

// Aggregation layer 2 v3 (unchanged from R9): linear walk of persisted sorted
// stream, edge-split lanes, butterfly combine; fused 16->64 matmul.
__global__ void __launch_bounds__(256) k_agg2(const void* __restrict__ x,
                                              const uint32_t* __restrict__ ssrc,
                                              const int* __restrict__ nof2,
                                              const int* __restrict__ gcnt,
                                              const bf16* __restrict__ zh,  // holds h
                                              const float* __restrict__ sa,
                                              const void* __restrict__ W2l,
                                              const void* __restrict__ b2l,
                                              const void* __restrict__ W2r,
                                              const void* __restrict__ b2r,
                                              const void* __restrict__ W2e,
                                              const void* __restrict__ b2e,
                                              void* __restrict__ out) {
    __shared__ uint32_t ss[CAP];         // 8 KB sorted src|dl stream
    __shared__ int snoff[BN];
    __shared__ float facc[BN * HID];     // 6.4 KB
    __shared__ bf16 hl[BN * HID];        // 3.2 KB
    __shared__ float w2l[HID * OUT_CH];  // 4 KB
    __shared__ float w2r[HID * OUT_CH];  // 4 KB
    __shared__ float swe[3 * HID];
    __shared__ float sbe[HID];
    __shared__ float sbb[OUT_CH];
    __shared__ int s_bf;
    int t = threadIdx.x;
    if (t == 0) s_bf = detect_bf(x);
    __syncthreads();
    int bf = s_bf;
    for (int i = t; i < HID * OUT_CH; i += 256) {
        w2l[i] = loadf(W2l, i, bf);
        w2r[i] = loadf(W2r, i, bf);
    }
    if (t < 3 * HID) swe[t] = loadf(W2e, t, bf);
    if (t < HID) sbe[t] = loadf(b2e, t, bf);
    if (t < OUT_CH) sbb[t] = loadf(b2l, t, bf) + loadf(b2r, t, bf);
    int b = blockIdx.x;
    int n = gcnt[b];
    if (n > CAP) n = CAP;
    for (int i = t; i < n; i += 256) ss[i] = ssrc[(size_t)b * BCAP + i];
    if (t < BN) snoff[t] = nof2[b * 128 + t];
    __syncthreads();
    int dl = t >> 1, half = t & 1, cs = half * 8;
    float acc[16];
#pragma unroll
    for (int j = 0; j < 16; ++j) acc[j] = 0.f;
    float degT = 0.f;
    if (dl < BN) {
        int kb = snoff[dl];
        int ke = (dl == BN - 1) ? n : snoff[dl + 1];
        degT = (float)(ke - kb);
        int k = kb + half;
        for (; k + 2 < ke; k += 4) {
            uint32_t s0 = ss[k], s1 = ss[k + 2];
            const uint32_t* r0 = (const uint32_t*)(zh + (size_t)(s0 & 0x1FFFFu) * HID);
            const uint32_t* r1 = (const uint32_t*)(zh + (size_t)(s1 & 0x1FFFFu) * HID);
            uint4 qa = *(const uint4*)r0;
            uint4 qb = *(const uint4*)(r0 + 4);
            uint4 qc = *(const uint4*)r1;
            uint4 qd = *(const uint4*)(r1 + 4);
            acc[0] += lo_f(qa.x) + lo_f(qc.x); acc[1] += hi_f(qa.x) + hi_f(qc.x);
            acc[2] += lo_f(qa.y) + lo_f(qc.y); acc[3] += hi_f(qa.y) + hi_f(qc.y);
            acc[4] += lo_f(qa.z) + lo_f(qc.z); acc[5] += hi_f(qa.z) + hi_f(qc.z);
            acc[6] += lo_f(qa.w) + lo_f(qc.w); acc[7] += hi_f(qa.w) + hi_f(qc.w);
            acc[8] += lo_f(qb.x) + lo_f(qd.x); acc[9] += hi_f(qb.x) + hi_f(qd.x);
            acc[10] += lo_f(qb.y) + lo_f(qd.y); acc[11] += hi_f(qb.y) + hi_f(qd.y);
            acc[12] += lo_f(qb.z) + lo_f(qd.z); acc[13] += hi_f(qb.z) + hi_f(qd.z);
            acc[14] += lo_f(qb.w) + lo_f(qd.w); acc[15] += hi_f(qb.w) + hi_f(qd.w);
        }
        for (; k < ke; k += 2) {
            uint32_t s0 = ss[k];
            const uint32_t* r0 = (const uint32_t*)(zh + (size_t)(s0 & 0x1FFFFu) * HID);
            uint4 qa = *(const uint4*)r0;
            uint4 qb = *(const uint4*)(r0 + 4);
            acc[0] += lo_f(qa.x); acc[1] += hi_f(qa.x);
            acc[2] += lo_f(qa.y); acc[3] += hi_f(qa.y);
            acc[4] += lo_f(qa.z); acc[5] += hi_f(qa.z);
            acc[6] += lo_f(qa.w); acc[7] += hi_f(qa.w);
            acc[8] += lo_f(qb.x); acc[9] += hi_f(qb.x);
            acc[10] += lo_f(qb.y); acc[11] += hi_f(qb.y);
            acc[12] += lo_f(qb.z); acc[13] += hi_f(qb.z);
            acc[14] += lo_f(qb.w); acc[15] += hi_f(qb.w);
        }
    }
    if (dl < BN) {
#pragma unroll
        for (int j = 0; j < 16; ++j) acc[j] += __shfl_xor(acc[j], 1);
        size_t i = (size_t)b * BN + dl;
        float inv = 1.0f / fmaxf(degT, 1.0f);
        float a0 = sa[i * 3 + 0], a1 = sa[i * 3 + 1], a2 = sa[i * 3 + 2];
        float4 f0, f1;
        float* fo = (float*)&f0;
        float* f1o = (float*)&f1;
#pragma unroll
        for (int j = 0; j < 4; ++j) {
            fo[j] = (acc[cs + j] + a0 * swe[cs + j] + a1 * swe[16 + cs + j] +
                     a2 * swe[32 + cs + j] + degT * sbe[cs + j]) * inv;
            f1o[j] = (acc[cs + 4 + j] + a0 * swe[cs + 4 + j] + a1 * swe[16 + cs + 4 + j] +
                      a2 * swe[32 + cs + 4 + j] + degT * sbe[cs + 4 + j]) * inv;
        }
        *(float4*)&facc[dl * HID + cs] = f0;
        *(float4*)&facc[dl * HID + cs + 4] = f1;
        *(uint4*)&hl[dl * HID + cs] = *(const uint4*)(zh + i * HID + cs);
    }
    __syncthreads();
    for (int idx = t; idx < BN * OUT_CH; idx += 256) {
        int dli = idx >> 6, j = idx & 63;
        size_t i = (size_t)b * BN + dli;
        float o = sbb[j];
#pragma unroll
        for (int cc = 0; cc < HID; ++cc)
            o += facc[dli * HID + cc] * w2l[cc * OUT_CH + j] +
                 b2f(hl[dli * HID + cc]) * w2r[cc * OUT_CH + j];
        if (bf)
            ((bf16*)out)[i * OUT_CH + j] = __float2bfloat16(o);
        else
            ((float*)out)[i * OUT_CH + j] = o;
    }
}

extern "C" void kernel_launch(void* const* d_in, const int* in_sizes, int n_in,
                              void* d_out, int out_size, void* d_ws, size_t ws_size,
                              hipStream_t stream) {
    const void* x   = d_in[0];
    const int*  ei  = (const int*)d_in[1];
    const void* ea  = d_in[2];
    const void* W1l = d_in[3];
    const void* b1l = d_in[4];
    const void* W1r = d_in[5];
    const void* b1r = d_in[6];
    const void* W1e = d_in[7];
    const void* b1e = d_in[8];
    const void* W2l = d_in[9];
    const void* b2l = d_in[10];
    const void* W2r = d_in[11];
    const void* b2r = d_in[12];
    const void* W2e = d_in[13];
    const void* b2e = d_in[14];

    const size_t N16 = (size_t)N_NODES * HID;
    char* p = (char*)d_ws;
    uint2*    slots = (uint2*)p;    p += (size_t)NB * BCAP * sizeof(uint2);     // 16.4 MB
    uint16_t* ea2v  = (uint16_t*)p; p += (size_t)NB * BCAP * sizeof(uint16_t);  // 4.1 MB
    uint32_t* ssrc  = (uint32_t*)p; p += (size_t)NB * BCAP * sizeof(uint32_t);  // 8.2 MB
    int*      nof2  = (int*)p;      p += (size_t)NB * 128 * sizeof(int);        // 0.5 MB
    bf16*     y     = (bf16*)p;     p += N16 * sizeof(bf16);                    // 3.2 MB
    bf16*     zh    = (bf16*)p;     p += N16 * sizeof(bf16);                    // 3.2 MB
    float*    sa    = (float*)p;    p += (size_t)3 * N_NODES * sizeof(float);   // 1.2 MB
    int*      gcnt  = (int*)p;      p += NB * sizeof(int);
    float*    wc    = (float*)p;    p += 64 * sizeof(float);
    // total ~37 MB

    hipMemsetAsync(gcnt, 0, NB * sizeof(int), stream);
    k_fused<<<F_GROUPS * 5, F_TPB, 0, stream>>>(x, ei, ea, W1l, W1r, b1l, b1r, W1e, b1e,
                                                y, zh, wc, gcnt, slots, ea2v);
    k_agg1<<<NB, 256, 0, stream>>>(slots, ea2v, gcnt, y, wc, zh, sa, ssrc, nof2);
    k_agg2<<<NB, 256, 0, stream>>>(x, ssrc, nof2, gcnt, zh, sa, W2l, b2l, W2r, b2r,
                                   W2e, b2e, d_out);
}

// Round 12
// 196.193 us; speedup vs baseline: 1.0309x; 1.0098x over previous
//
#include <hip/hip_runtime.h>
#include <hip/hip_bf16.h>
#include <stdint.h>

#define N_NODES 100000
#define N_EDGES 1200000
#define IN_CH 64
#define HID 16
#define OUT_CH 64

#define BN 100       // nodes per bucket (1000*100 == 100000 exactly)
#define NB 1000      // buckets
#define BCAP 2048    // fixed slot capacity per bucket (mean 1200, max ~1330 observed regime)
#define CAP 2048     // staged slots per chunk; n <= BCAP == CAP -> single chunk

// fused kernel geometry (R8 known-good: role-split blocks, 2 ky : 3 sc)
#define F_TPB 512
#define KY_BLOCKS ((N_NODES * 2 + F_TPB - 1) / F_TPB)   // 391
#define SC_EPB 2048
#define SC_EPT (SC_EPB / F_TPB)                          // 4 edges per thread
#define SC_BLOCKS ((N_EDGES + SC_EPB - 1) / SC_EPB)      // 586
#define F_GROUPS 196                                     // 196*5 = 980 blocks

#define A_TPB 512    // agg blocks: 512 threads, 4 lanes per node

typedef __hip_bfloat16 bf16;

__device__ __forceinline__ float b2f(bf16 v) { return __bfloat162float(v); }
__device__ __forceinline__ float lo_f(uint32_t p) { return __uint_as_float(p << 16); }
__device__ __forceinline__ float hi_f(uint32_t p) { return __uint_as_float(p & 0xffff0000u); }
__device__ __forceinline__ uint16_t f2bb(float v) {
    bf16 h = __float2bfloat16(v);
    return *reinterpret_cast<uint16_t*>(&h);
}

__device__ __forceinline__ float loadf(const void* p, size_t i, int bf) {
    return bf ? b2f(((const bf16*)p)[i]) : ((const float*)p)[i];
}
__device__ __forceinline__ uint32_t bfbits(const void* p, size_t i, int bf) {
    if (bf) return ((const uint16_t*)p)[i];
    return f2bb(((const float*)p)[i]);
}
__device__ __forceinline__ int ld_dst(const int* p, int j, int i64) {
    if (i64) return ((const int2*)p)[(size_t)N_EDGES + j].x;
    return p[(size_t)N_EDGES + j];
}
__device__ __forceinline__ int ld_src(const int* p, int j, int i64) {
    if (i64) return ((const int2*)p)[j].x;
    return p[j];
}

// dtype detection, replicated per block (64 broadcast loads, L1/L2-hot).
__device__ __forceinline__ int detect_bf(const void* x) {
    const uint16_t* u = (const uint16_t*)x;
    int cnt = 0;
    for (int i = 0; i < 64; ++i) {
        int e = (u[i] >> 7) & 0xff;
        cnt += (e >= 100 && e <= 140);
    }
    return cnt >= 50;
}
__device__ __forceinline__ int detect_i64(const int* ei) {
    const uint32_t* w = (const uint32_t*)ei;
    int z = 0;
    for (int i = 1; i < 64; i += 2) z += (w[i] == 0u);
    return z >= 16;
}

// Fused k_y + bscatter (R8 known-good, VERBATIM). Roles split by blockIdx, 2:3.
__global__ void __launch_bounds__(F_TPB) k_fused(const void* __restrict__ x,
                                                 const int* __restrict__ ei,
                                                 const void* __restrict__ ea,
                                                 const void* __restrict__ W1l,
                                                 const void* __restrict__ W1r,
                                                 const void* __restrict__ b1l,
                                                 const void* __restrict__ b1r,
                                                 const void* __restrict__ W1e,
                                                 const void* __restrict__ b1e,
                                                 bf16* __restrict__ y,
                                                 bf16* __restrict__ zh,
                                                 float* __restrict__ wc,
                                                 int* __restrict__ gcnt,
                                                 uint2* __restrict__ slots,
                                                 uint16_t* __restrict__ ea2v) {
    // union'd LDS: ky needs 8.3 KB, sc needs 35.7 KB
    __shared__ __align__(16) char smem[36608];
    __shared__ int wsum[8];
    __shared__ int s_flags;
    int t = threadIdx.x;
    int g = blockIdx.x / 5, r = blockIdx.x % 5;
    if (t == 0) s_flags = detect_bf(x) | (detect_i64(ei) << 1);

    if (r < 2) {
        // ---------------- ky role ----------------
        int kyid = g * 2 + r;
        if (kyid >= KY_BLOCKS) return;
        float* w = (float*)smem;            // [k][32]: cols 0-15 W1l, 16-31 W1r
        float* bz = (float*)(smem + 8192);  // [16]
        __syncthreads();
        int bf = s_flags & 1;
        for (int i = t; i < IN_CH * 32; i += F_TPB) {
            int k = i >> 5, cc = i & 31;
            w[i] = (cc < 16) ? loadf(W1l, k * HID + cc, bf)
                             : loadf(W1r, k * HID + (cc - 16), bf);
        }
        if (t < HID) bz[t] = loadf(b1l, t, bf) + loadf(b1r, t, bf);
        __syncthreads();
        if (kyid == 0 && t < HID) {
            int j = t;
            float s0 = 0.f, s1 = 0.f, s2 = 0.f, s3 = 0.f;
            for (int k = 0; k < IN_CH; ++k) {
                float wl = w[k * 32 + j];
                s0 += loadf(W1e, k, bf) * wl;
                s1 += loadf(W1e, IN_CH + k, bf) * wl;
                s2 += loadf(W1e, 2 * IN_CH + k, bf) * wl;
                s3 += loadf(b1e, k, bf) * wl;
            }
            wc[j] = s0;
            wc[HID + j] = s1;
            wc[2 * HID + j] = s2;
            wc[3 * HID + j] = s3;
        }
        int tid = kyid * F_TPB + t;
        int row = tid >> 1;
        if (row >= N_NODES) return;
        int half = tid & 1, cs = half * 16;
        float acc[16];
#pragma unroll
        for (int j = 0; j < 16; ++j) acc[j] = 0.f;
        if (bf) {
            const uint4* xr = (const uint4*)((const uint16_t*)x + (size_t)row * IN_CH);
            uint4 q[8];
#pragma unroll
            for (int i = 0; i < 8; ++i) q[i] = xr[i];
            const uint32_t* qq = (const uint32_t*)q;
#pragma unroll
            for (int k2 = 0; k2 < 32; ++k2) {
                uint32_t u = qq[k2];
                float x0 = lo_f(u), x1 = hi_f(u);
                const float* w0 = &w[(2 * k2) * 32 + cs];
                const float* w1 = w0 + 32;
#pragma unroll
                for (int j = 0; j < 16; ++j) acc[j] += x0 * w0[j] + x1 * w1[j];
            }
        } else {
            const float4* xr = (const float4*)((const float*)x + (size_t)row * IN_CH);
#pragma unroll
            for (int c = 0; c < 4; ++c) {
                float4 f[4];
#pragma unroll
                for (int i = 0; i < 4; ++i) f[i] = xr[c * 4 + i];
                const float* ff = (const float*)f;
#pragma unroll
                for (int kk = 0; kk < 16; ++kk) {
                    float xk = ff[kk];
                    const float* wr = &w[(c * 16 + kk) * 32 + cs];
#pragma unroll
                    for (int j = 0; j < 16; ++j) acc[j] += xk * wr[j];
                }
            }
        }
        if (half) {
#pragma unroll
            for (int j = 0; j < 16; ++j) acc[j] += bz[j];
        }
        uint32_t pk[8];
#pragma unroll
        for (int j2 = 0; j2 < 8; ++j2)
            pk[j2] = (uint32_t)f2bb(acc[2 * j2]) | ((uint32_t)f2bb(acc[2 * j2 + 1]) << 16);
        bf16* dst = half ? (zh + (size_t)row * HID) : (y + (size_t)row * HID);
        uint4* d4 = (uint4*)dst;
        d4[0] = make_uint4(pk[0], pk[1], pk[2], pk[3]);
        d4[1] = make_uint4(pk[4], pk[5], pk[6], pk[7]);
        return;
    }

    // ---------------- sc role ----------------
    int scid = g * 3 + (r - 2);
    if (scid >= SC_BLOCKS) return;
    uint2* lval = (uint2*)smem;                    // 16384 B
    int* lhist = (int*)(smem + 16384);             // 4000 B
    int* lscan = (int*)(smem + 20384);             // 4000 B
    int* ldelta = (int*)(smem + 24384);            // 4000 B
    uint16_t* lea = (uint16_t*)(smem + 28384);     // 4096 B
    uint16_t* lbid = (uint16_t*)(smem + 32480);    // 4096 B
    for (int i = t; i < NB; i += F_TPB) lhist[i] = 0;
    __syncthreads();
    int bf = s_flags & 1, i64 = (s_flags >> 1) & 1;
    int base = scid * SC_EPB;
    // Pass 1: load everything coalesced; rank within bucket via LDS atomic.
    // rb pack: b[28:19] dl[18:12] r[11:0]
    uint32_t rb[SC_EPT], srcv[SC_EPT], ea01v[SC_EPT], ea2r[SC_EPT];
#pragma unroll
    for (int i = 0; i < SC_EPT; ++i) {
        int e = base + i * F_TPB + t;
        rb[i] = 0xFFFFFFFFu;
        if (e < N_EDGES) {
            uint32_t d = (uint32_t)ld_dst(ei, e, i64);
            srcv[i] = (uint32_t)ld_src(ei, e, i64);
            ea01v[i] = bfbits(ea, (size_t)e * 3, bf) |
                       (bfbits(ea, (size_t)e * 3 + 1, bf) << 16);
            ea2r[i] = bfbits(ea, (size_t)e * 3 + 2, bf);
            uint32_t b = d / BN;
            uint32_t dl = d - b * BN;
            uint32_t rr = (uint32_t)atomicAdd(&lhist[b], 1);
            rb[i] = (b << 19) | (dl << 12) | rr;
        }
    }
    __syncthreads();
    // Pass 2: scan lhist (2 bins/thread, shfl wave-scan + LDS hop); reserve
    // per-bucket space in fixed region b*BCAP via global atomic.
    int b0 = 2 * t, b1 = 2 * t + 1;
    int cnt0 = (b0 < NB) ? lhist[b0] : 0;
    int cnt1 = (b1 < NB) ? lhist[b1] : 0;
    int s_local = cnt0 + cnt1;
    int incl = s_local;
    int lane = t & 63;
#pragma unroll
    for (int d = 1; d < 64; d <<= 1) {
        int v = __shfl_up(incl, d);
        if (lane >= d) incl += v;
    }
    int w = t >> 6;
    if (lane == 63) wsum[w] = incl;
    __syncthreads();
    int wbase = 0, nst = 0;
#pragma unroll
    for (int i = 0; i < 8; ++i) {
        int v = wsum[i];
        wbase += (i < w) ? v : 0;
        nst += v;
    }
    int run = wbase + incl - s_local;
    if (b0 < NB) {
        lscan[b0] = run;
        if (cnt0) ldelta[b0] = b0 * BCAP + atomicAdd(&gcnt[b0], cnt0) - run;
    }
    run += cnt0;
    if (b1 < NB) {
        lscan[b1] = run;
        if (cnt1) ldelta[b1] = b1 * BCAP + atomicAdd(&gcnt[b1], cnt1) - run;
    }
    __syncthreads();
    // Pass 3: stage at sorted position (values already in registers).
#pragma unroll
    for (int i = 0; i < SC_EPT; ++i) {
        if (rb[i] == 0xFFFFFFFFu) continue;
        uint32_t b = rb[i] >> 19;
        uint32_t dl = (rb[i] >> 12) & 0x7Fu;
        uint32_t rr = rb[i] & 0xFFFu;
        int lp = lscan[b] + (int)rr;
        lval[lp] = make_uint2(srcv[i] | (dl << 17), ea01v[i]);
        lea[lp] = (uint16_t)ea2r[i];
        lbid[lp] = (uint16_t)b;
    }
    __syncthreads();
    // Pass 4: write sorted -> consecutive lanes, consecutive addresses.
    for (int p = t; p < nst; p += F_TPB) {
        int b = lbid[p];
        int gp = ldelta[b] + p;
        slots[gp] = lval[p];
        ea2v[gp] = lea[p];
    }
}

// Aggregation layer 1 v4: 512 threads, 4 lanes/node edge-split gather
// (quarter = t&3 takes k = kb+q step 4; full 16-col accumulate; butterfly
// shfl_xor(1)+shfl_xor(2) combine). Counting sort writes sorted VALUES.
__global__ void __launch_bounds__(A_TPB) k_agg1(const uint2* __restrict__ slots,
                                                const uint16_t* __restrict__ ea2v,
                                                const int* __restrict__ gcnt,
                                                const bf16* __restrict__ y,
                                                const float* __restrict__ wc,
                                                bf16* __restrict__ zh,
                                                float* __restrict__ sa,
                                                uint32_t* __restrict__ ssrc,
                                                int* __restrict__ nof2) {
    __shared__ uint2 su[CAP];          // 16 KB staged {src|dl, ea01}
    __shared__ uint16_t ea2s[CAP];     // 4 KB staged ea2
    __shared__ uint32_t sst[CAP];      // 8 KB sorted src|dl
    __shared__ uint32_t sea01[CAP];    // 8 KB sorted ea01
    __shared__ uint16_t sea2[CAP];     // 4 KB sorted ea2
    __shared__ int hist[BN], noff[BN], cur[BN];
    __shared__ int wsum[8];
    __shared__ float swc[64];
    int t = threadIdx.x;
    if (t < 64) swc[t] = wc[t];
    int b = blockIdx.x;
    int n = gcnt[b];
    if (n > CAP) n = CAP;
    const uint2* sp = slots + (size_t)b * BCAP;
    const uint16_t* ep = ea2v + (size_t)b * BCAP;
    int dl = t >> 2, q = t & 3, cs = q * 4;

    for (int i = t; i < BN; i += A_TPB) hist[i] = 0;
    for (int i = t; i < n; i += A_TPB) {
        su[i] = sp[i];
        ea2s[i] = ep[i];
    }
    __syncthreads();
    for (int i = t; i < n; i += A_TPB) atomicAdd(&hist[su[i].x >> 17], 1);
    __syncthreads();
    // shfl-based exclusive scan of hist (1 bin/thread, 2 barriers)
    {
        int own = (t < BN) ? hist[t] : 0;
        int incl = own;
        int lane = t & 63;
#pragma unroll
        for (int d = 1; d < 64; d <<= 1) {
            int v = __shfl_up(incl, d);
            if (lane >= d) incl += v;
        }
        int w = t >> 6;
        if (lane == 63) wsum[w] = incl;
        __syncthreads();
        int wbase = 0;
#pragma unroll
        for (int i = 0; i < 8; ++i) wbase += (i < w) ? wsum[i] : 0;
        if (t < BN) {
            int ex = wbase + incl - own;
            noff[t] = ex;
            cur[t] = ex;
        }
        __syncthreads();
    }
    for (int i = t; i < n; i += A_TPB) {
        uint2 u2 = su[i];
        int r = atomicAdd(&cur[u2.x >> 17], 1);
        sst[r] = u2.x;
        sea01[r] = u2.y;
        sea2[r] = ea2s[i];
    }
    __syncthreads();
    for (int p = t; p < n; p += A_TPB) ssrc[(size_t)b * BCAP + p] = sst[p];
    if (t < BN) nof2[b * 128 + t] = noff[t];
    // per-node gather, 4-lane edge-split: lane takes k = kb+q, step 4
    float acc[16];
#pragma unroll
    for (int j = 0; j < 16; ++j) acc[j] = 0.f;
    float a0 = 0.f, a1 = 0.f, a2 = 0.f, degT = 0.f;
    if (dl < BN) {
        int kb = noff[dl];
        int ke = (dl == BN - 1) ? n : noff[dl + 1];
        degT = (float)(ke - kb);
        int k = kb + q;
        for (; k + 4 < ke; k += 8) {  // 2 edges in flight
            uint32_t s0 = sst[k], s1 = sst[k + 4];
            const uint32_t* r0 = (const uint32_t*)(y + (size_t)(s0 & 0x1FFFFu) * HID);
            const uint32_t* r1 = (const uint32_t*)(y + (size_t)(s1 & 0x1FFFFu) * HID);
            uint4 qa = *(const uint4*)r0;
            uint4 qb = *(const uint4*)(r0 + 4);
            uint4 qc = *(const uint4*)r1;
            uint4 qd = *(const uint4*)(r1 + 4);
            acc[0] += lo_f(qa.x) + lo_f(qc.x); acc[1] += hi_f(qa.x) + hi_f(qc.x);
            acc[2] += lo_f(qa.y) + lo_f(qc.y); acc[3] += hi_f(qa.y) + hi_f(qc.y);
            acc[4] += lo_f(qa.z) + lo_f(qc.z); acc[5] += hi_f(qa.z) + hi_f(qc.z);
            acc[6] += lo_f(qa.w) + lo_f(qc.w); acc[7] += hi_f(qa.w) + hi_f(qc.w);
            acc[8] += lo_f(qb.x) + lo_f(qd.x); acc[9] += hi_f(qb.x) + hi_f(qd.x);
            acc[10] += lo_f(qb.y) + lo_f(qd.y); acc[11] += hi_f(qb.y) + hi_f(qd.y);
            acc[12] += lo_f(qb.z) + lo_f(qd.z); acc[13] += hi_f(qb.z) + hi_f(qd.z);
            acc[14] += lo_f(qb.w) + lo_f(qd.w); acc[15] += hi_f(qb.w) + hi_f(qd.w);
            uint32_t e0 = sea01[k], e1 = sea01[k + 4];
            a0 += lo_f(e0) + lo_f(e1);
            a1 += hi_f(e0) + hi_f(e1);
            a2 += __uint_as_float((uint32_t)sea2[k] << 16) +
                  __uint_as_float((uint32_t)sea2[k + 4] << 16);
        }
        for (; k < ke; k += 4) {
            uint32_t s0 = sst[k];
            const uint32_t* r0 = (const uint32_t*)(y + (size_t)(s0 & 0x1FFFFu) * HID);
            uint4 qa = *(const uint4*)r0;
            uint4 qb = *(const uint4*)(r0 + 4);
            acc[0] += lo_f(qa.x); acc[1] += hi_f(qa.x);
            acc[2] += lo_f(qa.y); acc[3] += hi_f(qa.y);
            acc[4] += lo_f(qa.z); acc[5] += hi_f(qa.z);
            acc[6] += lo_f(qa.w); acc[7] += hi_f(qa.w);
            acc[8] += lo_f(qb.x); acc[9] += hi_f(qb.x);
            acc[10] += lo_f(qb.y); acc[11] += hi_f(qb.y);
            acc[12] += lo_f(qb.z); acc[13] += hi_f(qb.z);
            acc[14] += lo_f(qb.w); acc[15] += hi_f(qb.w);
            uint32_t e0 = sea01[k];
            a0 += lo_f(e0);
            a1 += hi_f(e0);
            a2 += __uint_as_float((uint32_t)sea2[k] << 16);
        }
    }
    // butterfly combine across the 4-lane group, then epilogue
    if (dl < BN) {
#pragma unroll
        for (int j = 0; j < 16; ++j) {
            acc[j] += __shfl_xor(acc[j], 1);
            acc[j] += __shfl_xor(acc[j], 2);
        }
        a0 += __shfl_xor(a0, 1); a0 += __shfl_xor(a0, 2);
        a1 += __shfl_xor(a1, 1); a1 += __shfl_xor(a1, 2);
        a2 += __shfl_xor(a2, 1); a2 += __shfl_xor(a2, 2);
        size_t i = (size_t)b * BN + dl;
        float inv = 1.0f / fmaxf(degT, 1.0f);
        uint2 zq = *(const uint2*)(zh + i * HID + cs);
        float zf[4] = {lo_f(zq.x), hi_f(zq.x), lo_f(zq.y), hi_f(zq.y)};
        uint32_t pk[2];
#pragma unroll
        for (int j = 0; j < 2; ++j) {
            int c0 = cs + 2 * j, c1 = cs + 2 * j + 1;
            float t0 = (acc[c0] + a0 * swc[c0] + a1 * swc[16 + c0] +
                        a2 * swc[32 + c0] + degT * swc[48 + c0]) * inv;
            float t1 = (acc[c1] + a0 * swc[c1] + a1 * swc[16 + c1] +
                        a2 * swc[32 + c1] + degT * swc[48 + c1]) * inv;
            float h0 = fmaxf(t0 + zf[2 * j], 0.f);
            float h1 = fmaxf(t1 + zf[2 * j + 1], 0.f);
            pk[j] = (uint32_t)f2bb(h0) | ((uint32_t)f2bb(h1) << 16);
        }
        *(uint2*)(zh + i * HID + cs) = make_uint2(pk[0], pk[1]);
        if (q == 0) {
            sa[i * 3 + 0] = a0;
            sa[i * 3 + 1] = a1;
            sa[i * 3 + 2] = a2;
        }
    }
}

// Aggregation layer 2 v4: 512 threads, 4 lanes/node edge-split walk of the
// persisted sorted stream; butterfly combine; fused 16->64 matmul.
__global__ void __launch_bounds__(A_TPB) k_agg2(const void* __restrict__ x,
                                                const uint32_t* __restrict__ ssrc,
                                                const int* __restrict__ nof2,
                                                const int* __restrict__ gcnt,
                                                const bf16* __restrict__ zh,  // holds h
                                                const float* __restrict__ sa,
                                                const void* __restrict__ W2l,
                                                const void* __restrict__ b2l,
                                                const void* __restrict__ W2r,
                                                const void* __restrict__ b2r,
                                                const void* __restrict__ W2e,
                                                const void* __restrict__ b2e,
                                                void* __restrict__ out) {
    __shared__ uint32_t ss[CAP];         // 8 KB sorted src|dl stream
    __shared__ int snoff[BN];
    __shared__ float facc[BN * HID];     // 6.4 KB
    __shared__ bf16 hl[BN * HID];        // 3.2 KB
    __shared__ float w2l[HID * OUT_CH];  // 4 KB
    __shared__ float w2r[HID * OUT_CH];  // 4 KB
    __shared__ float swe[3 * HID];
    __shared__ float sbe[HID];
    __shared__ float sbb[OUT_CH];
    __shared__ int s_bf;
    int t = threadIdx.x;
    if (t == 0) s_bf = detect_bf(x);
    __syncthreads();
    int bf = s_bf;
    for (int i = t; i < HID * OUT_CH; i += A_TPB) {
        w2l[i] = loadf(W2l, i, bf);
        w2r[i] = loadf(W2r, i, bf);
    }
    if (t < 3 * HID) swe[t] = loadf(W2e, t, bf);
    if (t < HID) sbe[t] = loadf(b2e, t, bf);
    if (t < OUT_CH) sbb[t] = loadf(b2l, t, bf) + loadf(b2r, t, bf);
    int b = blockIdx.x;
    int n = gcnt[b];
    if (n > CAP) n = CAP;
    for (int i = t; i < n; i += A_TPB) ss[i] = ssrc[(size_t)b * BCAP + i];
    if (t < BN) snoff[t] = nof2[b * 128 + t];
    __syncthreads();
    int dl = t >> 2, q = t & 3, cs = q * 4;
    float acc[16];
#pragma unroll
    for (int j = 0; j < 16; ++j) acc[j] = 0.f;
    float degT = 0.f;
    if (dl < BN) {
        int kb = snoff[dl];
        int ke = (dl == BN - 1) ? n : snoff[dl + 1];
        degT = (float)(ke - kb);
        int k = kb + q;
        for (; k + 4 < ke; k += 8) {
            uint32_t s0 = ss[k], s1 = ss[k + 4];
            const uint32_t* r0 = (const uint32_t*)(zh + (size_t)(s0 & 0x1FFFFu) * HID);
            const uint32_t* r1 = (const uint32_t*)(zh + (size_t)(s1 & 0x1FFFFu) * HID);
            uint4 qa = *(const uint4*)r0;
            uint4 qb = *(const uint4*)(r0 + 4);
            uint4 qc = *(const uint4*)r1;
            uint4 qd = *(const uint4*)(r1 + 4);
            acc[0] += lo_f(qa.x) + lo_f(qc.x); acc[1] += hi_f(qa.x) + hi_f(qc.x);
            acc[2] += lo_f(qa.y) + lo_f(qc.y); acc[3] += hi_f(qa.y) + hi_f(qc.y);
            acc[4] += lo_f(qa.z) + lo_f(qc.z); acc[5] += hi_f(qa.z) + hi_f(qc.z);
            acc[6] += lo_f(qa.w) + lo_f(qc.w); acc[7] += hi_f(qa.w) + hi_f(qc.w);
            acc[8] += lo_f(qb.x) + lo_f(qd.x); acc[9] += hi_f(qb.x) + hi_f(qd.x);
            acc[10] += lo_f(qb.y) + lo_f(qd.y); acc[11] += hi_f(qb.y) + hi_f(qd.y);
            acc[12] += lo_f(qb.z) + lo_f(qd.z); acc[13] += hi_f(qb.z) + hi_f(qd.z);
            acc[14] += lo_f(qb.w) + lo_f(qd.w); acc[15] += hi_f(qb.w) + hi_f(qd.w);
        }
        for (; k < ke; k += 4) {
            uint32_t s0 = ss[k];
            const uint32_t* r0 = (const uint32_t*)(zh + (size_t)(s0 & 0x1FFFFu) * HID);
            uint4 qa = *(const uint4*)r0;
            uint4 qb = *(const uint4*)(r0 + 4);
            acc[0] += lo_f(qa.x); acc[1] += hi_f(qa.x);
            acc[2] += lo_f(qa.y); acc[3] += hi_f(qa.y);
            acc[4] += lo_f(qa.z); acc[5] += hi_f(qa.z);
            acc[6] += lo_f(qa.w); acc[7] += hi_f(qa.w);
            acc[8] += lo_f(qb.x); acc[9] += hi_f(qb.x);
            acc[10] += lo_f(qb.y); acc[11] += hi_f(qb.y);
            acc[12] += lo_f(qb.z); acc[13] += hi_f(qb.z);
            acc[14] += lo_f(qb.w); acc[15] += hi_f(qb.w);
        }
    }
    // butterfly combine, then per-node mean path -> facc; self h -> hl
    if (dl < BN) {
#pragma unroll
        for (int j = 0; j < 16; ++j) {
            acc[j] += __shfl_xor(acc[j], 1);
            acc[j] += __shfl_xor(acc[j], 2);
        }
        size_t i = (size_t)b * BN + dl;
        float inv = 1.0f / fmaxf(degT, 1.0f);
        float a0 = sa[i * 3 + 0], a1 = sa[i * 3 + 1], a2 = sa[i * 3 + 2];
#pragma unroll
        for (int j = 0; j < 4; ++j) {
            int c = cs + j;
            facc[dl * HID + c] = (acc[c] + a0 * swe[c] + a1 * swe[16 + c] +
                                  a2 * swe[32 + c] + degT * sbe[c]) * inv;
        }
        *(uint2*)&hl[dl * HID + cs] = *(const uint2*)(zh + i * HID + cs);
    }
    __syncthreads();
    for (int idx = t; idx < BN * OUT_CH; idx += A_TPB) {
        int dli = idx >> 6, j = idx & 63;
        size_t i = (size_t)b * BN + dli;
        float o = sbb[j];
#pragma unroll
        for (int cc = 0; cc < HID; ++cc)
            o += facc[dli * HID + cc] * w2l[cc * OUT_CH + j] +
                 b2f(hl[dli * HID + cc]) * w2r[cc * OUT_CH + j];
        if (bf)
            ((bf16*)out)[i * OUT_CH + j] = __float2bfloat16(o);
        else
            ((float*)out)[i * OUT_CH + j] = o;
    }
}

extern "C" void kernel_launch(void* const* d_in, const int* in_sizes, int n_in,
                              void* d_out, int out_size, void* d_ws, size_t ws_size,
                              hipStream_t stream) {
    const void* x   = d_in[0];
    const int*  ei  = (const int*)d_in[1];
    const void* ea  = d_in[2];
    const void* W1l = d_in[3];
    const void* b1l = d_in[4];
    const void* W1r = d_in[5];
    const void* b1r = d_in[6];
    const void* W1e = d_in[7];
    const void* b1e = d_in[8];
    const void* W2l = d_in[9];
    const void* b2l = d_in[10];
    const void* W2r = d_in[11];
    const void* b2r = d_in[12];
    const void* W2e = d_in[13];
    const void* b2e = d_in[14];

    const size_t N16 = (size_t)N_NODES * HID;
    char* p = (char*)d_ws;
    uint2*    slots = (uint2*)p;    p += (size_t)NB * BCAP * sizeof(uint2);     // 16.4 MB
    uint16_t* ea2v  = (uint16_t*)p; p += (size_t)NB * BCAP * sizeof(uint16_t);  // 4.1 MB
    uint32_t* ssrc  = (uint32_t*)p; p += (size_t)NB * BCAP * sizeof(uint32_t);  // 8.2 MB
    int*      nof2  = (int*)p;      p += (size_t)NB * 128 * sizeof(int);        // 0.5 MB
    bf16*     y     = (bf16*)p;     p += N16 * sizeof(bf16);                    // 3.2 MB
    bf16*     zh    = (bf16*)p;     p += N16 * sizeof(bf16);                    // 3.2 MB
    float*    sa    = (float*)p;    p += (size_t)3 * N_NODES * sizeof(float);   // 1.2 MB
    int*      gcnt  = (int*)p;      p += NB * sizeof(int);
    float*    wc    = (float*)p;    p += 64 * sizeof(float);
    // total ~37 MB

    hipMemsetAsync(gcnt, 0, NB * sizeof(int), stream);
    k_fused<<<F_GROUPS * 5, F_TPB, 0, stream>>>(x, ei, ea, W1l, W1r, b1l, b1r, W1e, b1e,
                                                y, zh, wc, gcnt, slots, ea2v);
    k_agg1<<<NB, A_TPB, 0, stream>>>(slots, ea2v, gcnt, y, wc, zh, sa, ssrc, nof2);
    k_agg2<<<NB, A_TPB, 0, stream>>>(x, ssrc, nof2, gcnt, zh, sa, W2l, b2l, W2r, b2r,
                                     W2e, b2e, d_out);
}